// Round 7
// baseline (101.789 us; speedup 1.0000x reference)
//
#include <hip/hip_runtime.h>
#include <math.h>

#define NROWS 512      // b*c = 8*64
#define NFEAT 4968     // 2*207*12
#define NVEC4 1242     // NFEAT/4 float4 per row
#define KSLICES 6
#define SLICE4 207     // float4 per K-slice (1242/6)
#define GSL 1242       // gmm elements per slice (NFEAT/4)
#define FLAGCAP (1u << 22)
#define HALF_LOG2PI 0.91893853320467274178032973640562

// ---------------------------------------------------------------------------
// Phase 1: split-K row-tiled projection partials (f64) — unchanged.
// ---------------------------------------------------------------------------
__global__ __launch_bounds__(256) void proj_kernel(
    const float* __restrict__ x,
    const float* __restrict__ aw,
    const float* __restrict__ sw,
    const float* __restrict__ mw,
    double* __restrict__ pp)
{
    const int rt = blockIdx.x & 127;          // rowtile 0..127
    const int jg = (blockIdx.x >> 7) % 3;
    const int sl = blockIdx.x / 384;
    const int t = threadIdx.x;
    const int j = t >> 4;
    const int s16 = t & 15;
    const int row0 = rt * 4;

    const float* W = (jg == 0) ? aw : (jg == 1) ? sw : mw;
    const float4* wp = (const float4*)(W + (size_t)j * NFEAT) + sl * SLICE4;
    const float4* xp = (const float4*)(x + (size_t)row0 * NFEAT) + sl * SLICE4;

    double acc[4][2];
    #pragma unroll
    for (int r = 0; r < 4; ++r) { acc[r][0] = 0.0; acc[r][1] = 0.0; }

    for (int i = s16; i < SLICE4; i += 16) {
        float4 wv = wp[i];
        #pragma unroll
        for (int r = 0; r < 4; ++r) {
            float4 xv = xp[(size_t)r * NVEC4 + i];
            acc[r][0] = fma((double)xv.x, (double)wv.x, acc[r][0]);
            acc[r][0] = fma((double)xv.y, (double)wv.y, acc[r][0]);
            acc[r][1] = fma((double)xv.z, (double)wv.z, acc[r][1]);
            acc[r][1] = fma((double)xv.w, (double)wv.w, acc[r][1]);
        }
    }

    #pragma unroll
    for (int r = 0; r < 4; ++r) {
        double a = acc[r][0] + acc[r][1];
        #pragma unroll
        for (int off = 8; off; off >>= 1) a += __shfl_xor(a, off, 16);
        if (s16 == 0)
            pp[((size_t)(row0 + r) * 48 + jg * 16 + j) * KSLICES + sl] = a;
    }
}

// ---------------------------------------------------------------------------
// Phase 2: per-(row,k) parameter derivation (f64, bit-identical) + f32 copies.
// ---------------------------------------------------------------------------
__global__ __launch_bounds__(256) void params_kernel(
    const double* __restrict__ pp,
    const float* __restrict__ ab,
    const float* __restrict__ sb,
    const float* __restrict__ mb,
    double* __restrict__ mu, double* __restrict__ isg, double* __restrict__ cl,
    double* __restrict__ sig, double* __restrict__ ivp,
    float* __restrict__ muf, float* __restrict__ nhisg2f, float* __restrict__ clf,
    float* __restrict__ la, float* __restrict__ al,
    unsigned* __restrict__ flag_cnt)
{
    if (blockIdx.x == 0 && threadIdx.x == 0) *flag_cnt = 0u;

    const int g = blockIdx.x * 256 + threadIdx.x;   // 0..8191
    const int row = g >> 4, k = g & 15;
    const double* p = pp + ((size_t)row * 48 + k) * KSLICES;

    double pa = 0.0, ps = 0.0, pm = 0.0;
    #pragma unroll
    for (int s = 0; s < KSLICES; ++s) {
        pa += p[s];
        ps += p[16 * KSLICES + s];
        pm += p[32 * KSLICES + s];
    }
    pa += (double)ab[k]; ps += (double)sb[k]; pm += (double)mb[k];

    // softmax over 16 components (max-subtracted, like jax.nn.softmax)
    double m = pa;
    #pragma unroll
    for (int off = 8; off; off >>= 1) m = fmax(m, __shfl_xor(m, off, 16));
    double e = exp(pa - m);
    double ss = e;
    #pragma unroll
    for (int off = 8; off; off >>= 1) ss += __shfl_xor(ss, off, 16);
    double alpha = e / ss;
    double lav = log(alpha);

    double sg  = exp(ps);
    double lsg = log(sg);

    double isgv = 1.0 / sg;
    double clv  = lav - lsg - HALF_LOG2PI;   // lp = cl - 0.5*z^2

    mu[g]  = pm;
    isg[g] = isgv;
    cl[g]  = clv;
    sig[g] = sg;
    ivp[g] = 1.0 / (sg + 1e-5);
    muf[g]     = (float)pm;
    nhisg2f[g] = (float)(-0.5 * isgv * isgv);
    clf[g]     = (float)clv;
    la[g]  = (float)lav;
    al[g]  = (float)alpha;
}

// ---------------------------------------------------------------------------
// Phase 3: GMM pass, pure fp32 hot loop. Params PINNED in VGPRs via empty
// asm (prevents per-iteration reloads — r5/r6 pathology). 2048 blocks.
// ---------------------------------------------------------------------------
__global__ __launch_bounds__(256, 2) void gmm_kernel(
    const float* __restrict__ x,
    const float* __restrict__ muf, const float* __restrict__ nhisg2f,
    const float* __restrict__ clf, const float* __restrict__ laf,
    const double* __restrict__ sig, const double* __restrict__ ivp,
    float* __restrict__ out,
    float* __restrict__ S1p, float* __restrict__ S2p, float* __restrict__ FIp,
    unsigned* __restrict__ flag_cnt, unsigned* __restrict__ flag_list)
{
    const int row = blockIdx.x >> 2;
    const int sl  = blockIdx.x & 3;
    const int tid = threadIdx.x;
    const int g0  = row * 16;

    __shared__ double sig_s[16], ivp_s[16];
    __shared__ float  red[4][18];
    __shared__ float  tot_s[18];

    if (tid < 16) {
        sig_s[tid] = sig[g0 + tid];
        ivp_s[tid] = ivp[g0 + tid];
    }
    __syncthreads();

    float mu_r[16], ns_r[16], cl_r[16], la_r[16];
    #pragma unroll
    for (int k = 0; k < 16; ++k) {
        mu_r[k] = muf[g0 + k];
        ns_r[k] = nhisg2f[g0 + k];
        cl_r[k] = clf[g0 + k];
        la_r[k] = laf[g0 + k];
    }
    // Pin params in VGPRs: values become opaque -> cannot be re-loaded from
    // memory inside the loop, must stay register-resident.
    #pragma unroll
    for (int k = 0; k < 16; ++k) {
        asm volatile("" : "+v"(mu_r[k]), "+v"(ns_r[k]),
                          "+v"(cl_r[k]), "+v"(la_r[k]));
    }

    float S1[16];
    #pragma unroll
    for (int k = 0; k < 16; ++k) S1[k] = 0.f;
    float S2 = 0.f, FI = 0.f;

    const int base = sl * GSL;
    const float* xr = x + (size_t)row * NFEAT + base;
    float* outr = out + (size_t)row * NFEAT + base;

    for (int n = tid; n < GSL; n += 256) {
        float h = xr[n];
        float max1 = -3.4e38f, max2 = -3.4e38f;
        int lab = 0;
        float sumexp = 0.f, s1 = 0.f;
        #pragma unroll
        for (int k = 0; k < 16; ++k) {
            float d  = h - mu_r[k];
            float lp = fmaf(d * d, ns_r[k], cl_r[k]);
            max2 = fmaxf(fminf(lp, max1), max2);   // new 2nd max (branchless)
            lab  = (lp > max1) ? k : lab;
            max1 = fmaxf(lp, max1);
            float e   = __expf(lp);
            float lcp = lp - la_r[k];
            sumexp += e;
            s1 = fmaf(e, lcp, s1);
            S1[k] += lcp;
        }
        S2 += __logf(sumexp);        // log-sum-exp WITHOUT max-sub (matches ref)
        FI += s1 / sumexp;

        double sg = sig_s[lab];
        outr[n] = (float)(((double)h - sg) * ivp_s[lab]);

        if (max1 - max2 < 1e-3f) {   // rare near-tie -> defer exact f64 argmax
            unsigned idx = atomicAdd(flag_cnt, 1u);
            if (idx < FLAGCAP)
                flag_list[idx] = (unsigned)(row * NFEAT + base + n);
        }
    }

    // --- block-reduce 18 accumulators ---
    float vals[18];
    #pragma unroll
    for (int i = 0; i < 16; ++i) vals[i] = S1[i];
    vals[16] = S2; vals[17] = FI;

    #pragma unroll
    for (int i = 0; i < 18; ++i) {
        float v = vals[i];
        #pragma unroll
        for (int off = 32; off; off >>= 1) v += __shfl_xor(v, off, 64);
        vals[i] = v;
    }
    const int wave = tid >> 6, lane = tid & 63;
    if (lane == 0) {
        #pragma unroll
        for (int i = 0; i < 18; ++i) red[wave][i] = vals[i];
    }
    __syncthreads();
    if (tid < 18)
        tot_s[tid] = red[0][tid] + red[1][tid] + red[2][tid] + red[3][tid];
    __syncthreads();
    if (tid < 16) S1p[(size_t)blockIdx.x * 16 + tid] = tot_s[tid];
    if (tid == 16) S2p[blockIdx.x] = tot_s[16];
    if (tid == 17) FIp[blockIdx.x] = tot_s[17];
}

// ---------------------------------------------------------------------------
// Phase 4: single-block tail — exact f64 fixup for flagged elements
// (bit-identical argmax/output) + deterministic loss reduce.
// ---------------------------------------------------------------------------
__global__ __launch_bounds__(1024) void tail_kernel(
    const float* __restrict__ x,
    const double* __restrict__ mu, const double* __restrict__ isg,
    const double* __restrict__ cl,
    const double* __restrict__ sig, const double* __restrict__ ivp,
    const unsigned* __restrict__ flag_cnt, const unsigned* __restrict__ flag_list,
    const float* __restrict__ S1p, const float* __restrict__ S2p,
    const float* __restrict__ FIp,
    const float* __restrict__ la, const float* __restrict__ al,
    float* __restrict__ out, float* __restrict__ loss_out)
{
    const int tid = threadIdx.x;

    // ---- fixup (independent of loss part; no barrier needed) ----
    unsigned cnt = *flag_cnt;
    if (cnt > FLAGCAP) cnt = FLAGCAP;
    for (unsigned i = tid; i < cnt; i += 1024) {
        unsigned eid = flag_list[i];
        int row = (int)(eid / NFEAT);
        int g0 = row * 16;
        double hd = (double)x[eid];
        double maxlp = -1.0e300;
        int lab = 0;
        #pragma unroll
        for (int k = 0; k < 16; ++k) {
            double zd  = (hd - mu[g0 + k]) * isg[g0 + k];
            double lpd = fma(zd * zd, -0.5, cl[g0 + k]);
            if (lpd > maxlp) { maxlp = lpd; lab = k; }
        }
        out[eid] = (float)((hd - sig[g0 + lab]) * ivp[g0 + lab]);
    }

    // ---- loss reduce ----
    const float invN = 1.0f / (float)NFEAT;
    float kl_acc = 0.f;
    for (int g = tid; g < 8192; g += 1024) {
        int row = g >> 4, k = g & 15;
        int b = row * 4;
        float s1 = S1p[(size_t)(b + 0) * 16 + k] + S1p[(size_t)(b + 1) * 16 + k]
                 + S1p[(size_t)(b + 2) * 16 + k] + S1p[(size_t)(b + 3) * 16 + k];
        float s2 = S2p[b + 0] + S2p[b + 1] + S2p[b + 2] + S2p[b + 3];
        float lav = la[g], alv = al[g];
        float q = s1 * invN + lav - s2 * invN;
        kl_acc += alv * (lav - q);
    }
    float fi_acc = 0.f;
    for (int i = tid; i < 2048; i += 1024) fi_acc += FIp[i];

    #pragma unroll
    for (int off = 32; off; off >>= 1) {
        kl_acc += __shfl_xor(kl_acc, off, 64);
        fi_acc += __shfl_xor(fi_acc, off, 64);
    }
    __shared__ float ra[16], rb[16];
    const int wave = tid >> 6, lane = tid & 63;
    if (lane == 0) { ra[wave] = kl_acc; rb[wave] = fi_acc; }
    __syncthreads();
    if (tid == 0) {
        float ka = 0.f, kb = 0.f;
        #pragma unroll
        for (int i = 0; i < 16; ++i) { ka += ra[i]; kb += rb[i]; }
        // kl mean over (b,c,K)=8192 ; first_item mean over (b,c,N,K)=40697856
        loss_out[0] = ka / 8192.0f - kb / 40697856.0f;
    }
}

extern "C" void kernel_launch(void* const* d_in, const int* in_sizes, int n_in,
                              void* d_out, int out_size, void* d_ws, size_t ws_size,
                              hipStream_t stream) {
    const float* x  = (const float*)d_in[0];
    const float* aw = (const float*)d_in[1];
    const float* ab = (const float*)d_in[2];
    const float* sw = (const float*)d_in[3];
    const float* sb = (const float*)d_in[4];
    const float* mw = (const float*)d_in[5];
    const float* mb = (const float*)d_in[6];
    float* out = (float*)d_out;

    double* pp  = (double*)d_ws;                        // 512*48*6 f64
    double* mu  = pp + (size_t)NROWS * 48 * KSLICES;
    double* isg = mu + 8192;
    double* cl  = isg + 8192;
    double* sig = cl + 8192;
    double* ivp = sig + 8192;
    float* muf     = (float*)(ivp + 8192);
    float* nhisg2f = muf + 8192;
    float* clf     = nhisg2f + 8192;
    float* la      = clf + 8192;
    float* al      = la + 8192;
    float* S1p  = al + 8192;                // 2048*16
    float* S2p  = S1p + 2048 * 16;          // 2048
    float* FIp  = S2p + 2048;               // 2048
    unsigned* flag_cnt  = (unsigned*)(FIp + 2048);
    unsigned* flag_list = flag_cnt + 16;    // up to FLAGCAP entries

    proj_kernel<<<128 * 3 * KSLICES, 256, 0, stream>>>(x, aw, sw, mw, pp);
    params_kernel<<<32, 256, 0, stream>>>(pp, ab, sb, mb,
                                          mu, isg, cl, sig, ivp,
                                          muf, nhisg2f, clf, la, al, flag_cnt);
    gmm_kernel<<<NROWS * 4, 256, 0, stream>>>(x, muf, nhisg2f, clf, la, sig, ivp,
                                              out, S1p, S2p, FIp,
                                              flag_cnt, flag_list);
    tail_kernel<<<1, 1024, 0, stream>>>(x, mu, isg, cl, sig, ivp,
                                        flag_cnt, flag_list,
                                        S1p, S2p, FIp, la, al,
                                        out, out + (size_t)NROWS * NFEAT);
}

// Round 8
// 70.375 us; speedup vs baseline: 1.4464x; 1.4464x over previous
//
#include <hip/hip_runtime.h>
#include <math.h>

#define NROWS 512      // b*c = 8*64
#define NFEAT 4968     // 2*207*12
#define NVEC4 1242     // NFEAT/4 float4 per row
#define KSLICES 6
#define SLICE4 207     // float4 per K-slice (1242/6)
#define GSL 1242       // gmm elements per slice (NFEAT/4)
#define NGBLK (NROWS * 4)          // 2048 gmm blocks
#define WPB 20                     // flag words per gmm block: 5 iters * 4 waves
#define NWORDS (NGBLK * WPB)       // 40960
#define HALF_LOG2PI 0.91893853320467274178032973640562

// ---------------------------------------------------------------------------
// Phase 1: split-K row-tiled projection partials (f64) — unchanged.
// ---------------------------------------------------------------------------
__global__ __launch_bounds__(256) void proj_kernel(
    const float* __restrict__ x,
    const float* __restrict__ aw,
    const float* __restrict__ sw,
    const float* __restrict__ mw,
    double* __restrict__ pp)
{
    const int rt = blockIdx.x & 127;          // rowtile 0..127
    const int jg = (blockIdx.x >> 7) % 3;
    const int sl = blockIdx.x / 384;
    const int t = threadIdx.x;
    const int j = t >> 4;
    const int s16 = t & 15;
    const int row0 = rt * 4;

    const float* W = (jg == 0) ? aw : (jg == 1) ? sw : mw;
    const float4* wp = (const float4*)(W + (size_t)j * NFEAT) + sl * SLICE4;
    const float4* xp = (const float4*)(x + (size_t)row0 * NFEAT) + sl * SLICE4;

    double acc[4][2];
    #pragma unroll
    for (int r = 0; r < 4; ++r) { acc[r][0] = 0.0; acc[r][1] = 0.0; }

    for (int i = s16; i < SLICE4; i += 16) {
        float4 wv = wp[i];
        #pragma unroll
        for (int r = 0; r < 4; ++r) {
            float4 xv = xp[(size_t)r * NVEC4 + i];
            acc[r][0] = fma((double)xv.x, (double)wv.x, acc[r][0]);
            acc[r][0] = fma((double)xv.y, (double)wv.y, acc[r][0]);
            acc[r][1] = fma((double)xv.z, (double)wv.z, acc[r][1]);
            acc[r][1] = fma((double)xv.w, (double)wv.w, acc[r][1]);
        }
    }

    #pragma unroll
    for (int r = 0; r < 4; ++r) {
        double a = acc[r][0] + acc[r][1];
        #pragma unroll
        for (int off = 8; off; off >>= 1) a += __shfl_xor(a, off, 16);
        if (s16 == 0)
            pp[((size_t)(row0 + r) * 48 + jg * 16 + j) * KSLICES + sl] = a;
    }
}

// ---------------------------------------------------------------------------
// Phase 2: per-(row,k) parameter derivation (f64, bit-identical math).
// ---------------------------------------------------------------------------
__global__ __launch_bounds__(256) void params_kernel(
    const double* __restrict__ pp,
    const float* __restrict__ ab,
    const float* __restrict__ sb,
    const float* __restrict__ mb,
    double* __restrict__ mu, double* __restrict__ isg, double* __restrict__ cl,
    double* __restrict__ sig, double* __restrict__ ivp, double* __restrict__ lsg_o,
    float* __restrict__ muf, float* __restrict__ nhisg2f, float* __restrict__ clf,
    float* __restrict__ la, float* __restrict__ al)
{
    const int g = blockIdx.x * 256 + threadIdx.x;   // 0..8191
    const int row = g >> 4, k = g & 15;
    const double* p = pp + ((size_t)row * 48 + k) * KSLICES;

    double pa = 0.0, ps = 0.0, pm = 0.0;
    #pragma unroll
    for (int s = 0; s < KSLICES; ++s) {
        pa += p[s];
        ps += p[16 * KSLICES + s];
        pm += p[32 * KSLICES + s];
    }
    pa += (double)ab[k]; ps += (double)sb[k]; pm += (double)mb[k];

    // softmax over 16 components (max-subtracted, like jax.nn.softmax)
    double m = pa;
    #pragma unroll
    for (int off = 8; off; off >>= 1) m = fmax(m, __shfl_xor(m, off, 16));
    double e = exp(pa - m);
    double ss = e;
    #pragma unroll
    for (int off = 8; off; off >>= 1) ss += __shfl_xor(ss, off, 16);
    double alpha = e / ss;
    double lav = log(alpha);

    double sg  = exp(ps);
    double lsg = log(sg);

    double isgv = 1.0 / sg;
    double clv  = lav - lsg - HALF_LOG2PI;   // lp = cl - 0.5*z^2

    mu[g]  = pm;
    isg[g] = isgv;
    cl[g]  = clv;
    sig[g] = sg;
    ivp[g] = 1.0 / (sg + 1e-5);
    lsg_o[g] = lsg;
    muf[g]     = (float)pm;
    nhisg2f[g] = (float)(-0.5 * isgv * isgv);
    clf[g]     = (float)clv;
    la[g]  = (float)lav;
    al[g]  = (float)alpha;
}

// ---------------------------------------------------------------------------
// Phase 3: GMM pass, pure fp32 hot loop, params pinned in VGPRs, NO atomics.
// Near-ties recorded via per-wave ballot -> one plain store per wave-iter.
// Loss needs only sum(h), sum(h^2) (f64), S2, FI per block.
// ---------------------------------------------------------------------------
__global__ __launch_bounds__(256, 2) void gmm_kernel(
    const float* __restrict__ x,
    const float* __restrict__ muf, const float* __restrict__ nhisg2f,
    const float* __restrict__ clf, const float* __restrict__ laf,
    const double* __restrict__ sig, const double* __restrict__ ivp,
    float* __restrict__ out,
    double* __restrict__ shp, double* __restrict__ sh2p,
    float* __restrict__ S2p, float* __restrict__ FIp,
    unsigned long long* __restrict__ flagwords)
{
    const int row = blockIdx.x >> 2;
    const int sl  = blockIdx.x & 3;
    const int tid = threadIdx.x;
    const int g0  = row * 16;

    __shared__ double sig_s[16], ivp_s[16];
    __shared__ double redd[4][2];
    __shared__ float  redf[4][2];

    if (tid < 16) {
        sig_s[tid] = sig[g0 + tid];
        ivp_s[tid] = ivp[g0 + tid];
    }
    __syncthreads();

    float mu_r[16], ns_r[16], cl_r[16], la_r[16];
    #pragma unroll
    for (int k = 0; k < 16; ++k) {
        mu_r[k] = muf[g0 + k];
        ns_r[k] = nhisg2f[g0 + k];
        cl_r[k] = clf[g0 + k];
        la_r[k] = laf[g0 + k];
    }
    // Pin params in VGPRs (prevents per-iteration rematerializing loads).
    #pragma unroll
    for (int k = 0; k < 16; ++k) {
        asm volatile("" : "+v"(mu_r[k]), "+v"(ns_r[k]),
                          "+v"(cl_r[k]), "+v"(la_r[k]));
    }

    double sh = 0.0, sh2 = 0.0;
    float S2 = 0.f, FI = 0.f;

    const int base = sl * GSL;
    const float* xr = x + (size_t)row * NFEAT + base;
    float* outr = out + (size_t)row * NFEAT + base;
    const int wave = tid >> 6;
    unsigned long long* fw = flagwords + (size_t)blockIdx.x * WPB;

    for (int it = 0, n = tid; n < GSL; ++it, n += 256) {
        float h = xr[n];
        float max1 = -3.4e38f, max2 = -3.4e38f;
        int lab = 0;
        float sumexp = 0.f, s1 = 0.f;
        #pragma unroll
        for (int k = 0; k < 16; ++k) {
            float d  = h - mu_r[k];
            float lp = fmaf(d * d, ns_r[k], cl_r[k]);
            max2 = fmaxf(fminf(lp, max1), max2);   // 2nd max (branchless)
            lab  = (lp > max1) ? k : lab;
            max1 = fmaxf(lp, max1);
            float e = __expf(lp);
            sumexp += e;
            s1 = fmaf(e, lp - la_r[k], s1);
        }
        S2 += __logf(sumexp);        // log-sum-exp WITHOUT max-sub (matches ref)
        FI += s1 / sumexp;
        sh += (double)h;
        sh2 = fma((double)h, (double)h, sh2);

        double sg = sig_s[lab];
        outr[n] = (float)(((double)h - sg) * ivp_s[lab]);

        // near-tie bitmap: one plain store per wave per iter, no atomics
        unsigned long long mask = __ballot(max1 - max2 < 1e-3f);
        if ((tid & 63) == 0) fw[it * 4 + wave] = mask;
    }

    // --- block-reduce {sh, sh2 (f64), S2, FI (f32)} ---
    #pragma unroll
    for (int off = 32; off; off >>= 1) {
        sh  += __shfl_xor(sh,  off, 64);
        sh2 += __shfl_xor(sh2, off, 64);
        S2  += __shfl_xor(S2,  off, 64);
        FI  += __shfl_xor(FI,  off, 64);
    }
    const int lane = tid & 63;
    if (lane == 0) {
        redd[wave][0] = sh;  redd[wave][1] = sh2;
        redf[wave][0] = S2;  redf[wave][1] = FI;
    }
    __syncthreads();
    if (tid == 0) {
        shp[blockIdx.x]  = redd[0][0] + redd[1][0] + redd[2][0] + redd[3][0];
        sh2p[blockIdx.x] = redd[0][1] + redd[1][1] + redd[2][1] + redd[3][1];
        S2p[blockIdx.x]  = redf[0][0] + redf[1][0] + redf[2][0] + redf[3][0];
        FIp[blockIdx.x]  = redf[0][1] + redf[1][1] + redf[2][1] + redf[3][1];
    }
}

// ---------------------------------------------------------------------------
// Phase 3b: parallel exact-f64 fixup, scanning the ballot bitmap.
// Bit-identical argmax/output formula. 128 blocks.
// ---------------------------------------------------------------------------
__global__ __launch_bounds__(256) void fixup_kernel(
    const float* __restrict__ x,
    const double* __restrict__ mu, const double* __restrict__ isg,
    const double* __restrict__ cl,
    const double* __restrict__ sig, const double* __restrict__ ivp,
    const unsigned long long* __restrict__ flagwords,
    float* __restrict__ out)
{
    for (int w = blockIdx.x * 256 + threadIdx.x; w < NWORDS; w += 128 * 256) {
        unsigned long long bits = flagwords[w];
        if (!bits) continue;
        const int blk  = w / WPB;
        const int r20  = w - blk * WPB;
        const int it   = r20 >> 2;
        const int wave = r20 & 3;
        const int row  = blk >> 2;
        const int sl   = blk & 3;
        const int g0   = row * 16;
        const int nbase = it * 256 + wave * 64;
        while (bits) {
            int b = __builtin_ctzll(bits);
            bits &= bits - 1;
            int n = nbase + b;
            if (n >= GSL) continue;
            size_t eid = (size_t)row * NFEAT + sl * GSL + n;
            double hd = (double)x[eid];
            double maxlp = -1.0e300;
            int lab = 0;
            #pragma unroll
            for (int k = 0; k < 16; ++k) {
                double zd  = (hd - mu[g0 + k]) * isg[g0 + k];
                double lpd = fma(zd * zd, -0.5, cl[g0 + k]);
                if (lpd > maxlp) { maxlp = lpd; lab = k; }
            }
            out[eid] = (float)((hd - sig[g0 + lab]) * ivp[g0 + lab]);
        }
    }
}

// ---------------------------------------------------------------------------
// Phase 4: single-block loss reduce. S1_k computed ANALYTICALLY (lp is
// quadratic in h): S1_k = N*(-lsg_k - c0) + ns_k*(sh2 - 2 mu_k sh + N mu_k^2).
// KL term: alpha*(la - q) = alpha*(S2_row - S1_k)/N  (la cancels).
// ---------------------------------------------------------------------------
__global__ __launch_bounds__(1024) void loss_kernel(
    const double* __restrict__ shp, const double* __restrict__ sh2p,
    const float* __restrict__ S2p, const float* __restrict__ FIp,
    const double* __restrict__ mu, const double* __restrict__ isg,
    const double* __restrict__ lsg, const float* __restrict__ al,
    float* __restrict__ loss_out)
{
    const int tid = threadIdx.x;
    const double Nd = (double)NFEAT;

    double kl_acc = 0.0;
    for (int g = tid; g < 8192; g += 1024) {
        int row = g >> 4;
        int b = row * 4;
        double sh  = shp[b + 0] + shp[b + 1] + shp[b + 2] + shp[b + 3];
        double sh2 = sh2p[b + 0] + sh2p[b + 1] + sh2p[b + 2] + sh2p[b + 3];
        float  s2f = S2p[b + 0] + S2p[b + 1] + S2p[b + 2] + S2p[b + 3];
        double m  = mu[g];
        double iv = isg[g];
        double ns = -0.5 * iv * iv;
        double S1 = Nd * (-lsg[g] - HALF_LOG2PI)
                  + ns * (sh2 - 2.0 * m * sh + Nd * m * m);
        kl_acc += (double)al[g] * ((double)s2f - S1) / Nd;
    }
    float fi_acc = 0.f;
    for (int i = tid; i < 2048; i += 1024) fi_acc += FIp[i];

    #pragma unroll
    for (int off = 32; off; off >>= 1) {
        kl_acc += __shfl_xor(kl_acc, off, 64);
        fi_acc += __shfl_xor(fi_acc, off, 64);
    }
    __shared__ double ra[16];
    __shared__ float  rb[16];
    const int wave = tid >> 6, lane = tid & 63;
    if (lane == 0) { ra[wave] = kl_acc; rb[wave] = fi_acc; }
    __syncthreads();
    if (tid == 0) {
        double ka = 0.0; float kb = 0.f;
        #pragma unroll
        for (int i = 0; i < 16; ++i) { ka += ra[i]; kb += rb[i]; }
        // kl mean over (b,c,K)=8192 ; first_item mean over (b,c,N,K)=40697856
        loss_out[0] = (float)(ka / 8192.0 - (double)kb / 40697856.0);
    }
}

extern "C" void kernel_launch(void* const* d_in, const int* in_sizes, int n_in,
                              void* d_out, int out_size, void* d_ws, size_t ws_size,
                              hipStream_t stream) {
    const float* x  = (const float*)d_in[0];
    const float* aw = (const float*)d_in[1];
    const float* ab = (const float*)d_in[2];
    const float* sw = (const float*)d_in[3];
    const float* sb = (const float*)d_in[4];
    const float* mw = (const float*)d_in[5];
    const float* mb = (const float*)d_in[6];
    float* out = (float*)d_out;

    double* pp   = (double*)d_ws;                       // 512*48*6 f64
    double* mu   = pp + (size_t)NROWS * 48 * KSLICES;
    double* isg  = mu + 8192;
    double* cl   = isg + 8192;
    double* sig  = cl + 8192;
    double* ivp  = sig + 8192;
    double* lsg  = ivp + 8192;
    double* shp  = lsg + 8192;              // 2048 f64
    double* sh2p = shp + NGBLK;             // 2048 f64
    unsigned long long* flagwords = (unsigned long long*)(sh2p + NGBLK); // 40960
    float* muf     = (float*)(flagwords + NWORDS);
    float* nhisg2f = muf + 8192;
    float* clf     = nhisg2f + 8192;
    float* la      = clf + 8192;
    float* al      = la + 8192;
    float* S2p     = al + 8192;             // 2048
    float* FIp     = S2p + NGBLK;           // 2048

    proj_kernel<<<128 * 3 * KSLICES, 256, 0, stream>>>(x, aw, sw, mw, pp);
    params_kernel<<<32, 256, 0, stream>>>(pp, ab, sb, mb,
                                          mu, isg, cl, sig, ivp, lsg,
                                          muf, nhisg2f, clf, la, al);
    gmm_kernel<<<NGBLK, 256, 0, stream>>>(x, muf, nhisg2f, clf, la, sig, ivp,
                                          out, shp, sh2p, S2p, FIp, flagwords);
    fixup_kernel<<<128, 256, 0, stream>>>(x, mu, isg, cl, sig, ivp,
                                          flagwords, out);
    loss_kernel<<<1, 1024, 0, stream>>>(shp, sh2p, S2p, FIp,
                                        mu, isg, lsg, al,
                                        out + (size_t)NROWS * NFEAT);
}